// Round 1
// baseline (242.677 us; speedup 1.0000x reference)
//
#include <hip/hip_runtime.h>
#include <hip/hip_bf16.h>

// Problem constants (fixed instance)
#define T_TOK 2048
#define K_DIM 2048
#define I_DIM 1024
#define NE    8
#define TOPK  2
#define GS    64

#define NSLOT  (T_TOK * TOPK)      // 4096 routed slots
#define TOTROW (NSLOT + T_TOK)     // + shared-expert rows = 6144
#define MAXITEM 32                 // max (expert, 256-row m-tile) work items

typedef __attribute__((ext_vector_type(8))) short short8;   // 8 bf16 (MFMA A/B frag)
typedef __attribute__((ext_vector_type(4))) float f32x4;    // MFMA C/D frag

// ---- workspace layout (bytes) ----
// 0: gcnt[16] | 64: gbase[16] | 128: tileCnt | 192: tileE[64] | 448: tileM[64]
// 1024: tok[6144] | 25600: inv[4096]
#define WS_XB   ((size_t)65536)                        // ushort xb[2048][2048]
#define WS_ACT  (WS_XB  + (size_t)2048 * 2048 * 2)     // ushort act[TOTROW][1024]
#define WS_Y    (WS_ACT + (size_t)TOTROW * 1024 * 2)   // ushort y[TOTROW][2048]
// total ~46 MB (fp4->bf16 dequant is fused into the GEMMs; no materialized weights)

// k-permutation sigma = {0,2,4,6,1,3,5,7} within each 8-block on BOTH operands
// (dot-product invariant); falls out of the byte-parallel nibble decode.

__device__ __forceinline__ unsigned pack2(float a, float b) {
    __hip_bfloat162 h = __float22bfloat162_rn(make_float2(a, b)); // x=low
    return *reinterpret_cast<unsigned*>(&h);
}

__device__ __forceinline__ unsigned scale2(unsigned p, float s) {
    float f0 = __uint_as_float(p << 16) * s;
    float f1 = __uint_as_float(p & 0xFFFF0000u) * s;
    return pack2(f0, f1);
}

__device__ __forceinline__ float bf2f(ushort h) {
    return __uint_as_float((unsigned)h << 16);
}

// one packed word (8 fp4 along k) -> 8 bf16 (sigma k-order) scaled by s
__device__ __forceinline__ void dq_word(unsigned w, float s, unsigned o[4]) {
    unsigned lo  = w & 0x0F0F0F0Fu;
    unsigned hi  = (w >> 4) & 0x0F0F0F0Fu;
    unsigned mlo = lo & 0x07070707u, mhi = hi & 0x07070707u;
    unsigned Hlo = __builtin_amdgcn_perm(0x40404040u, 0x3F3F3F00u, mlo);
    unsigned Hhi = __builtin_amdgcn_perm(0x40404040u, 0x3F3F3F00u, mhi);
    unsigned Llo = __builtin_amdgcn_perm(0xC0804000u, 0xC0800000u, mlo);
    unsigned Lhi = __builtin_amdgcn_perm(0xC0804000u, 0xC0800000u, mhi);
    Hlo |= (lo & 0x08080808u) << 4;
    Hhi |= (hi & 0x08080808u) << 4;
    unsigned e01 = __builtin_amdgcn_perm(Hlo, Llo, 0x05010400u);
    unsigned e23 = __builtin_amdgcn_perm(Hlo, Llo, 0x07030602u);
    unsigned o01 = __builtin_amdgcn_perm(Hhi, Lhi, 0x05010400u);
    unsigned o23 = __builtin_amdgcn_perm(Hhi, Lhi, 0x07030602u);
    o[0] = scale2(e01, s); o[1] = scale2(e23, s);
    o[2] = scale2(o01, s); o[3] = scale2(o23, s);
}

__device__ __forceinline__ void gld16(const void* g, void* l) {
    __builtin_amdgcn_global_load_lds(
        (const __attribute__((address_space(1))) unsigned*)g,
        (__attribute__((address_space(3))) unsigned*)l, 16, 0, 0);
}

// ---- front end: x prep + routing (weight dequant is fused into the GEMMs)
#define PREP_BLK 2048
#define FRONT_GRID (PREP_BLK + 1)

__global__ __launch_bounds__(256) void k_front(
        const float* __restrict__ x, ushort* __restrict__ xb,
        const int* __restrict__ eids,
        int* __restrict__ gcnt, int* __restrict__ gbase,
        int* __restrict__ tileCnt, int* __restrict__ tileE, int* __restrict__ tileM,
        int* __restrict__ tok, int* __restrict__ inv) {
    int id = blockIdx.x;
    int tid = threadIdx.x;

    if (id < PREP_BLK) {                              // x fp32 -> sigma-bf16
        int idx = id * 256 + tid;
        const float4* p = (const float4*)(x + (size_t)idx * 8);
        float4 f0 = p[0], f1 = p[1];
        unsigned u0 = pack2(f0.x, f0.z);
        unsigned u1 = pack2(f1.x, f1.z);
        unsigned u2 = pack2(f0.y, f0.w);
        unsigned u3 = pack2(f1.y, f1.w);
        *(int4*)(xb + (size_t)idx * 8) = make_int4(u0, u1, u2, u3);
    } else {                                           // routing + work-list
        __shared__ int lcnt[NE], lbase[NE], lcur[NE];
        if (tid < NE) lcnt[tid] = 0;
        __syncthreads();
        for (int i = tid; i < NSLOT; i += 256)
            atomicAdd(&lcnt[eids[i]], 1);
        __syncthreads();
        if (tid == 0) {
            int acc = 0;
            for (int e = 0; e < NE; e++) { lbase[e] = acc; acc += lcnt[e]; }
        }
        __syncthreads();
        if (tid < NE) lcur[tid] = lbase[tid];
        __syncthreads();
        for (int i = tid; i < NSLOT; i += 256) {
            int e = eids[i];
            int pos = atomicAdd(&lcur[e], 1);
            tok[pos] = i >> 1;
            inv[i] = pos;
        }
        for (int t = tid; t < T_TOK; t += 256)
            tok[NSLOT + t] = t;
        if (tid < NE) { gcnt[tid] = lcnt[tid]; gbase[tid] = lbase[tid]; }
        if (tid == 0) {
            gcnt[NE] = T_TOK; gbase[NE] = NSLOT;
            int nt = 0;
            for (int e = 0; e < NE + 1; e++) {
                int c = (e < NE) ? lcnt[e] : T_TOK;
                for (int m = 0; m < c; m += 256) { tileE[nt] = e; tileM[nt] = m; nt++; }
            }
            *tileCnt = nt;                             // <= 32
            for (int i = nt; i < 64; i++) { tileE[i] = 0; tileM[i] = 0; }
        }
    }
}

// ---- GEMM 1: act[p,n] = silu(x@Wg)*(x@Wu). 256 rows x (128 gate + 128 up) per
// block, 1024 threads = 16 waves of the verified 64x64 wave-tile / BK=64 /
// XOR-swizzle inner loop. B (gate_up weights) is dequanted fp4->bf16 IN the
// staging path: each thread owns one B-column and 2 k-words per k-step,
// ds_writes into the same swizzled layout (LDS[r][c] = G[r][c^(r&7)]) the
// MFMA fragment reads expect. Next-step packed/scale loads are issued before
// the barrier so their latency hides under the MFMA phase.
__global__ __launch_bounds__(1024) void k_gemm_gateup(
        const ushort* __restrict__ xb,
        const int* __restrict__ gup, const float* __restrict__ gus,
        const int* __restrict__ sup, const float* __restrict__ sus,
        const int* __restrict__ gcnt, const int* __restrict__ gbase,
        const int* __restrict__ tileCnt, const int* __restrict__ tileE,
        const int* __restrict__ tileM,
        const int* __restrict__ tokid, ushort* __restrict__ act) {
    int item = blockIdx.y;
    if (item >= *tileCnt) return;
    int tid = threadIdx.x;
    int e = tileE[item], m0 = tileM[item];
    int cnt = gcnt[e], base = gbase[e];
    int n0 = blockIdx.x * 128;                         // act cols per block
    const int* wp; const float* sc;
    if (e < NE) { wp = gup + (size_t)e * 256 * 2048; sc = gus + (size_t)e * 32 * 2048; }
    else        { wp = sup; sc = sus; }

    __shared__ __align__(16) ushort xs[256 * 64];      // 32 KB
    __shared__ __align__(16) ushort bs[256 * 64];      // 32 KB

    int lane = tid & 63, wv = tid >> 6;                // 16 waves
    int lid = lane & 15, quad = lane >> 4;
    int wr = wv >> 2, wc = wv & 3;                     // 4x4 waves of 64x64
    int l8 = lane >> 3, l7 = lane & 7;
    int chunk = (l7 ^ l8) * 8;

    // A staging: 2 rows per lane, global_load_lds with pre-swizzled source
    const ushort* aSrc[2];
    #pragma unroll
    for (int it = 0; it < 2; it++) {
        int rA = wv * 16 + it * 8 + l8;                // rA & 7 == l8
        int t = (m0 + rA < cnt) ? tokid[base + m0 + rA] : 0;
        aSrc[it] = xb + (size_t)t * K_DIM + chunk;
    }

    // B fused dequant: thread owns column nloc, k-chunks {kw0, kw0+1} of each
    // 64-k step. ds_write dest carries the XOR swizzle; packed-word source is
    // linear (contiguous 128B segments per wave across nloc).
    int nloc = tid & 255;
    int kw0 = (tid >> 8) * 2;
    int bj = nloc & 63, bh = nloc >> 6;
    int ncol = (bj < 32) ? (n0 + bh * 32 + bj) : (I_DIM + n0 + bh * 32 + (bj - 32));
    ushort* bd0 = &bs[nloc * 64 + ((kw0    ) ^ (nloc & 7)) * 8];
    ushort* bd1 = &bs[nloc * 64 + ((kw0 + 1) ^ (nloc & 7)) * 8];

    float s   = sc[ncol];                              // k-group 0
    unsigned w0 = (unsigned)wp[(size_t)(kw0    ) * 2048 + ncol];
    unsigned w1 = (unsigned)wp[(size_t)(kw0 + 1) * 2048 + ncol];

    f32x4 acc[4][4] = {};

    for (int k0 = 0; k0 < K_DIM; k0 += 64) {
        #pragma unroll
        for (int it = 0; it < 2; it++)
            gld16(aSrc[it] + k0, &xs[(wv * 2 + it) * 512]);
        {
            unsigned o[4];
            dq_word(w0, s, o);
            *(int4*)bd0 = make_int4(o[0], o[1], o[2], o[3]);
            dq_word(w1, s, o);
            *(int4*)bd1 = make_int4(o[0], o[1], o[2], o[3]);
        }
        int kn = k0 + 64;
        if (kn < K_DIM) {                              // prefetch next k-step B
            s  = sc[(size_t)(kn >> 6) * 2048 + ncol];
            w0 = (unsigned)wp[(size_t)((kn >> 3) + kw0    ) * 2048 + ncol];
            w1 = (unsigned)wp[(size_t)((kn >> 3) + kw0 + 1) * 2048 + ncol];
        }
        __syncthreads();
        #pragma unroll
        for (int ks = 0; ks < 2; ks++) {
            int slot = ((ks * 4 + quad) ^ l7) * 8;
            short8 a[4], b[4];
            #pragma unroll
            for (int mt = 0; mt < 4; mt++)
                a[mt] = *(const short8*)&xs[(wr * 64 + mt * 16 + lid) * 64 + slot];
            #pragma unroll
            for (int nt = 0; nt < 4; nt++)
                b[nt] = *(const short8*)&bs[(wc * 64 + nt * 16 + lid) * 64 + slot];
            #pragma unroll
            for (int mt = 0; mt < 4; mt++)
                #pragma unroll
                for (int nt = 0; nt < 4; nt++)
                    acc[mt][nt] = __builtin_amdgcn_mfma_f32_16x16x32_bf16(
                        a[mt], b[nt], acc[mt][nt], 0, 0, 0);
        }
        __syncthreads();
    }

    int c7 = lid & 7;
    int delta = ((c7 >> 1) + ((c7 & 1) << 2)) - c7;   // sigma^-1 on stored I index
    #pragma unroll
    for (int mt = 0; mt < 4; mt++) {
        #pragma unroll
        for (int i = 0; i < 4; i++) {
            int row = wr * 64 + mt * 16 + quad * 4 + i;
            if (m0 + row < cnt) {
                size_t p = (size_t)(base + m0 + row);
                #pragma unroll
                for (int nt = 0; nt < 2; nt++) {
                    float g = acc[mt][nt][i], u = acc[mt][nt + 2][i];
                    float vv = g / (1.f + __expf(-g)) * u;
                    int ncol2 = n0 + wc * 32 + nt * 16 + lid;
                    __hip_bfloat16 hb = __float2bfloat16(vv);
                    act[p * I_DIM + ncol2 + delta] = *reinterpret_cast<ushort*>(&hb);
                }
            }
        }
    }
}

// ---- GEMM 2: y[p,n] = (act @ Wd)[p,n]. 256 rows x 256 cols, 1024 threads.
// B (down weights) dequanted fp4->bf16 in staging, same scheme as GEMM 1.
__global__ __launch_bounds__(1024) void k_gemm_down(
        const ushort* __restrict__ actb,
        const int* __restrict__ dwp, const float* __restrict__ dsc,
        const int* __restrict__ sdp, const float* __restrict__ sds,
        const int* __restrict__ gcnt, const int* __restrict__ gbase,
        const int* __restrict__ tileCnt, const int* __restrict__ tileE,
        const int* __restrict__ tileM,
        ushort* __restrict__ y) {
    int item = blockIdx.y;
    if (item >= *tileCnt) return;
    int tid = threadIdx.x;
    int e = tileE[item], m0 = tileM[item];
    int cnt = gcnt[e], base = gbase[e];
    int n0 = blockIdx.x * 256;
    const int* wp; const float* sc;
    if (e < NE) { wp = dwp + (size_t)e * 128 * 2048; sc = dsc + (size_t)e * 16 * 2048; }
    else        { wp = sdp; sc = sds; }

    __shared__ __align__(16) ushort xs[256 * 64];
    __shared__ __align__(16) ushort bs[256 * 64];

    int lane = tid & 63, wv = tid >> 6;
    int lid = lane & 15, quad = lane >> 4;
    int wr = wv >> 2, wc = wv & 3;
    int l8 = lane >> 3, l7 = lane & 7;
    int chunk = (l7 ^ l8) * 8;

    const ushort* aSrc[2];
    #pragma unroll
    for (int it = 0; it < 2; it++) {
        int rA = wv * 16 + it * 8 + l8;
        int rr = m0 + rA; if (rr >= cnt) rr = cnt - 1;
        aSrc[it] = actb + (size_t)(base + rr) * I_DIM + chunk;
    }

    int nloc = tid & 255;
    int kw0 = (tid >> 8) * 2;
    int ncol = n0 + nloc;
    ushort* bd0 = &bs[nloc * 64 + ((kw0    ) ^ (nloc & 7)) * 8];
    ushort* bd1 = &bs[nloc * 64 + ((kw0 + 1) ^ (nloc & 7)) * 8];

    float s   = sc[ncol];                              // i-group 0
    unsigned w0 = (unsigned)wp[(size_t)(kw0    ) * 2048 + ncol];
    unsigned w1 = (unsigned)wp[(size_t)(kw0 + 1) * 2048 + ncol];

    f32x4 acc[4][4] = {};

    for (int i0 = 0; i0 < I_DIM; i0 += 64) {
        #pragma unroll
        for (int it = 0; it < 2; it++)
            gld16(aSrc[it] + i0, &xs[(wv * 2 + it) * 512]);
        {
            unsigned o[4];
            dq_word(w0, s, o);
            *(int4*)bd0 = make_int4(o[0], o[1], o[2], o[3]);
            dq_word(w1, s, o);
            *(int4*)bd1 = make_int4(o[0], o[1], o[2], o[3]);
        }
        int in0 = i0 + 64;
        if (in0 < I_DIM) {                             // prefetch next i-step B
            s  = sc[(size_t)(in0 >> 6) * 2048 + ncol];
            w0 = (unsigned)wp[(size_t)((in0 >> 3) + kw0    ) * 2048 + ncol];
            w1 = (unsigned)wp[(size_t)((in0 >> 3) + kw0 + 1) * 2048 + ncol];
        }
        __syncthreads();
        #pragma unroll
        for (int ks = 0; ks < 2; ks++) {
            int slot = ((ks * 4 + quad) ^ l7) * 8;
            short8 a[4], b[4];
            #pragma unroll
            for (int mt = 0; mt < 4; mt++)
                a[mt] = *(const short8*)&xs[(wr * 64 + mt * 16 + lid) * 64 + slot];
            #pragma unroll
            for (int nt = 0; nt < 4; nt++)
                b[nt] = *(const short8*)&bs[(wc * 64 + nt * 16 + lid) * 64 + slot];
            #pragma unroll
            for (int mt = 0; mt < 4; mt++)
                #pragma unroll
                for (int nt = 0; nt < 4; nt++)
                    acc[mt][nt] = __builtin_amdgcn_mfma_f32_16x16x32_bf16(
                        a[mt], b[nt], acc[mt][nt], 0, 0, 0);
        }
        __syncthreads();
    }

    #pragma unroll
    for (int mt = 0; mt < 4; mt++) {
        #pragma unroll
        for (int i = 0; i < 4; i++) {
            int row = wr * 64 + mt * 16 + quad * 4 + i;
            if (m0 + row < cnt) {
                ushort* yrow = y + (size_t)(base + m0 + row) * 2048 + n0 + wc * 64 + lid;
                #pragma unroll
                for (int nt = 0; nt < 4; nt++) {
                    __hip_bfloat16 hb = __float2bfloat16(acc[mt][nt][i]);
                    yrow[nt * 16] = *reinterpret_cast<ushort*>(&hb);
                }
            }
        }
    }
}

// out[t] = p0*y[inv[2t]] + p1*y[inv[2t+1]] + y[NSLOT+t]
__global__ __launch_bounds__(256) void k_combine(
        const ushort* __restrict__ y, const int* __restrict__ inv,
        const float* __restrict__ prb, float* __restrict__ out) {
    int idx = blockIdx.x * 256 + threadIdx.x;
    int t = idx >> 8;
    int c = (idx & 255) * 8;
    int p0 = inv[2 * t], p1 = inv[2 * t + 1];
    float w0 = prb[2 * t], w1 = prb[2 * t + 1];
    int4 a = *(const int4*)(y + (size_t)p0 * 2048 + c);
    int4 b = *(const int4*)(y + (size_t)p1 * 2048 + c);
    int4 s = *(const int4*)(y + (size_t)(NSLOT + t) * 2048 + c);
    const ushort* au = (const ushort*)&a;
    const ushort* bu = (const ushort*)&b;
    const ushort* su = (const ushort*)&s;
    float o[8];
    #pragma unroll
    for (int j = 0; j < 8; j++)
        o[j] = w0 * bf2f(au[j]) + w1 * bf2f(bu[j]) + bf2f(su[j]);
    *(float4*)(out + (size_t)t * 2048 + c)     = *(float4*)&o[0];
    *(float4*)(out + (size_t)t * 2048 + c + 4) = *(float4*)&o[4];
}

extern "C" void kernel_launch(void* const* d_in, const int* in_sizes, int n_in,
                              void* d_out, int out_size, void* d_ws, size_t ws_size,
                              hipStream_t stream) {
    const float* x    = (const float*)d_in[0];
    const int*   gup  = (const int*)d_in[1];
    const float* gus  = (const float*)d_in[2];
    const int*   dwp  = (const int*)d_in[3];
    const float* dsc  = (const float*)d_in[4];
    const int*   sup  = (const int*)d_in[5];
    const float* sus  = (const float*)d_in[6];
    const int*   sdp  = (const int*)d_in[7];
    const float* sds  = (const float*)d_in[8];
    const int*   eids = (const int*)d_in[9];
    const float* prb  = (const float*)d_in[10];
    float* out = (float*)d_out;

    char*   ws      = (char*)d_ws;
    int*    gcnt    = (int*)(ws + 0);
    int*    gbase   = (int*)(ws + 64);
    int*    tileCnt = (int*)(ws + 128);
    int*    tileE   = (int*)(ws + 192);
    int*    tileM   = (int*)(ws + 448);
    int*    tok     = (int*)(ws + 1024);
    int*    inv     = (int*)(ws + 25600);
    ushort* xb      = (ushort*)(ws + WS_XB);
    ushort* act     = (ushort*)(ws + WS_ACT);
    ushort* y       = (ushort*)(ws + WS_Y);

    k_front<<<FRONT_GRID, 256, 0, stream>>>(
        x, xb, eids, gcnt, gbase, tileCnt, tileE, tileM, tok, inv);
    k_gemm_gateup<<<dim3(I_DIM / 128, MAXITEM), 1024, 0, stream>>>(
        xb, gup, gus, sup, sus, gcnt, gbase, tileCnt, tileE, tileM, tok, act);
    k_gemm_down<<<dim3(K_DIM / 256, MAXITEM), 1024, 0, stream>>>(
        act, dwp, dsc, sdp, sds, gcnt, gbase, tileCnt, tileE, tileM, y);
    k_combine<<<(T_TOK * K_DIM / 8) / 256, 256, 0, stream>>>(y, inv, prb, out);
}

// Round 2
// 232.402 us; speedup vs baseline: 1.0442x; 1.0442x over previous
//
#include <hip/hip_runtime.h>
#include <hip/hip_bf16.h>

// Problem constants (fixed instance)
#define T_TOK 2048
#define K_DIM 2048
#define I_DIM 1024
#define NE    8
#define TOPK  2
#define GS    64

#define NSLOT  (T_TOK * TOPK)      // 4096 routed slots
#define TOTROW (NSLOT + T_TOK)     // + shared-expert rows = 6144
#define MAXITEM 32                 // max (expert, 256-row m-tile) work items

typedef __attribute__((ext_vector_type(8))) short short8;   // 8 bf16 (MFMA A/B frag)
typedef __attribute__((ext_vector_type(4))) float f32x4;    // MFMA C/D frag

// ---- workspace layout (bytes) ----
// 0: gcnt[16] | 64: gbase[16] | 128: tileCnt | 192: tileE[64] | 448: tileM[64]
// 1024: tok[6144] | 25600: inv[4096]
#define WS_XB   ((size_t)65536)                        // ushort xb[2048][2048]
#define WS_ACT  (WS_XB  + (size_t)2048 * 2048 * 2)     // ushort act[TOTROW][1024]
#define WS_Y    (WS_ACT + (size_t)TOTROW * 1024 * 2)   // ushort y[TOTROW][2048]
// total ~46 MB (fp4->bf16 dequant fused into the GEMMs; no materialized weights)

// k-permutation sigma = {0,2,4,6,1,3,5,7} within each 8-block on BOTH operands
// (dot-product invariant); falls out of the byte-parallel nibble decode.

__device__ __forceinline__ unsigned pack2(float a, float b) {
    __hip_bfloat162 h = __float22bfloat162_rn(make_float2(a, b)); // x=low
    return *reinterpret_cast<unsigned*>(&h);
}

__device__ __forceinline__ unsigned scale2(unsigned p, float s) {
    float f0 = __uint_as_float(p << 16) * s;
    float f1 = __uint_as_float(p & 0xFFFF0000u) * s;
    return pack2(f0, f1);
}

__device__ __forceinline__ float bf2f(ushort h) {
    return __uint_as_float((unsigned)h << 16);
}

// one packed word (8 fp4 along k) -> 8 bf16 (sigma k-order) scaled by s
__device__ __forceinline__ void dq_word(unsigned w, float s, unsigned o[4]) {
    unsigned lo  = w & 0x0F0F0F0Fu;
    unsigned hi  = (w >> 4) & 0x0F0F0F0Fu;
    unsigned mlo = lo & 0x07070707u, mhi = hi & 0x07070707u;
    unsigned Hlo = __builtin_amdgcn_perm(0x40404040u, 0x3F3F3F00u, mlo);
    unsigned Hhi = __builtin_amdgcn_perm(0x40404040u, 0x3F3F3F00u, mhi);
    unsigned Llo = __builtin_amdgcn_perm(0xC0804000u, 0xC0800000u, mlo);
    unsigned Lhi = __builtin_amdgcn_perm(0xC0804000u, 0xC0800000u, mhi);
    Hlo |= (lo & 0x08080808u) << 4;
    Hhi |= (hi & 0x08080808u) << 4;
    unsigned e01 = __builtin_amdgcn_perm(Hlo, Llo, 0x05010400u);
    unsigned e23 = __builtin_amdgcn_perm(Hlo, Llo, 0x07030602u);
    unsigned o01 = __builtin_amdgcn_perm(Hhi, Lhi, 0x05010400u);
    unsigned o23 = __builtin_amdgcn_perm(Hhi, Lhi, 0x07030602u);
    o[0] = scale2(e01, s); o[1] = scale2(e23, s);
    o[2] = scale2(o01, s); o[3] = scale2(o23, s);
}

__device__ __forceinline__ void gld16(const void* g, void* l) {
    __builtin_amdgcn_global_load_lds(
        (const __attribute__((address_space(1))) unsigned*)g,
        (__attribute__((address_space(3))) unsigned*)l, 16, 0, 0);
}

// ---- front end: x prep + routing (weight dequant is fused into the GEMMs)
#define PREP_BLK 2048
#define FRONT_GRID (PREP_BLK + 1)

__global__ __launch_bounds__(256) void k_front(
        const float* __restrict__ x, ushort* __restrict__ xb,
        const int* __restrict__ eids,
        int* __restrict__ gcnt, int* __restrict__ gbase,
        int* __restrict__ tileCnt, int* __restrict__ tileE, int* __restrict__ tileM,
        int* __restrict__ tok, int* __restrict__ inv) {
    int id = blockIdx.x;
    int tid = threadIdx.x;

    if (id < PREP_BLK) {                              // x fp32 -> sigma-bf16
        int idx = id * 256 + tid;
        const float4* p = (const float4*)(x + (size_t)idx * 8);
        float4 f0 = p[0], f1 = p[1];
        unsigned u0 = pack2(f0.x, f0.z);
        unsigned u1 = pack2(f1.x, f1.z);
        unsigned u2 = pack2(f0.y, f0.w);
        unsigned u3 = pack2(f1.y, f1.w);
        *(int4*)(xb + (size_t)idx * 8) = make_int4(u0, u1, u2, u3);
    } else {                                           // routing + work-list
        __shared__ int lcnt[NE], lbase[NE], lcur[NE];
        if (tid < NE) lcnt[tid] = 0;
        __syncthreads();
        for (int i = tid; i < NSLOT; i += 256)
            atomicAdd(&lcnt[eids[i]], 1);
        __syncthreads();
        if (tid == 0) {
            int acc = 0;
            for (int e = 0; e < NE; e++) { lbase[e] = acc; acc += lcnt[e]; }
        }
        __syncthreads();
        if (tid < NE) lcur[tid] = lbase[tid];
        __syncthreads();
        for (int i = tid; i < NSLOT; i += 256) {
            int e = eids[i];
            int pos = atomicAdd(&lcur[e], 1);
            tok[pos] = i >> 1;
            inv[i] = pos;
        }
        for (int t = tid; t < T_TOK; t += 256)
            tok[NSLOT + t] = t;
        if (tid < NE) { gcnt[tid] = lcnt[tid]; gbase[tid] = lbase[tid]; }
        if (tid == 0) {
            gcnt[NE] = T_TOK; gbase[NE] = NSLOT;
            int nt = 0;
            for (int e = 0; e < NE + 1; e++) {
                int c = (e < NE) ? lcnt[e] : T_TOK;
                for (int m = 0; m < c; m += 256) { tileE[nt] = e; tileM[nt] = m; nt++; }
            }
            *tileCnt = nt;                             // <= 32
            for (int i = nt; i < 64; i++) { tileE[i] = 0; tileM[i] = 0; }
        }
    }
}

// ---- GEMM 1: act[p,n] = silu(x@Wg)*(x@Wu). 256 rows x (128 gate + 128 up) per
// block, 1024 threads = 16 waves of 64x64 wave-tiles / BK=64 / XOR-swizzle.
// Single-barrier double-buffered pipeline: per k-step, issue A global_load_lds
// for tile t+1 + dequant B(t+1) (fp4->bf16 in registers, ds_write swizzled)
// into buf^1, prefetch packed words for t+2, then MFMA tile t from buf.
// One __syncthreads per k-step: dequant VALU + A-load latency hide under the
// ~615-cycle MFMA phase (separate pipes; waves slip).
__global__ __launch_bounds__(1024) void k_gemm_gateup(
        const ushort* __restrict__ xb,
        const int* __restrict__ gup, const float* __restrict__ gus,
        const int* __restrict__ sup, const float* __restrict__ sus,
        const int* __restrict__ gcnt, const int* __restrict__ gbase,
        const int* __restrict__ tileCnt, const int* __restrict__ tileE,
        const int* __restrict__ tileM,
        const int* __restrict__ tokid, ushort* __restrict__ act) {
    int item = blockIdx.y;
    if (item >= *tileCnt) return;
    int tid = threadIdx.x;
    int e = tileE[item], m0 = tileM[item];
    int cnt = gcnt[e], base = gbase[e];
    int n0 = blockIdx.x * 128;                         // act cols per block
    const int* wp; const float* sc;
    if (e < NE) { wp = gup + (size_t)e * 256 * 2048; sc = gus + (size_t)e * 32 * 2048; }
    else        { wp = sup; sc = sus; }

    __shared__ __align__(16) ushort xs[2][256 * 64];   // 2 x 32 KB
    __shared__ __align__(16) ushort bs[2][256 * 64];   // 2 x 32 KB (128 KB total)

    int lane = tid & 63, wv = tid >> 6;                // 16 waves
    int lid = lane & 15, quad = lane >> 4;
    int wr = wv >> 2, wc = wv & 3;                     // 4x4 waves of 64x64
    int l8 = lane >> 3, l7 = lane & 7;
    int chunk = (l7 ^ l8) * 8;

    // A staging: 2 rows per lane, global_load_lds with pre-swizzled source
    const ushort* aSrc[2];
    #pragma unroll
    for (int it = 0; it < 2; it++) {
        int rA = wv * 16 + it * 8 + l8;                // rA & 7 == l8
        int t = (m0 + rA < cnt) ? tokid[base + m0 + rA] : 0;
        aSrc[it] = xb + (size_t)t * K_DIM + chunk;
    }

    // B fused dequant: thread owns column nloc, k-words {kw0, kw0+1} per step
    int nloc = tid & 255;
    int kw0 = (tid >> 8) * 2;
    int bj = nloc & 63, bh = nloc >> 6;
    int ncol = (bj < 32) ? (n0 + bh * 32 + bj) : (I_DIM + n0 + bh * 32 + (bj - 32));
    int bd0 = nloc * 64 + ((kw0    ) ^ (nloc & 7)) * 8;
    int bd1 = nloc * 64 + ((kw0 + 1) ^ (nloc & 7)) * 8;

    const int NT = K_DIM / 64;                         // 32 k-tiles

    // prologue: tile 0 into buf 0
    #pragma unroll
    for (int it = 0; it < 2; it++)
        gld16(aSrc[it], &xs[0][(wv * 2 + it) * 512]);
    float s   = sc[ncol];
    unsigned w0 = (unsigned)wp[(size_t)(kw0    ) * 2048 + ncol];
    unsigned w1 = (unsigned)wp[(size_t)(kw0 + 1) * 2048 + ncol];
    {
        unsigned o[4];
        dq_word(w0, s, o); *(int4*)&bs[0][bd0] = make_int4(o[0], o[1], o[2], o[3]);
        dq_word(w1, s, o); *(int4*)&bs[0][bd1] = make_int4(o[0], o[1], o[2], o[3]);
    }
    // prefetch tile 1 packed words
    s  = sc[(size_t)2048 + ncol];
    w0 = (unsigned)wp[(size_t)(8 + kw0    ) * 2048 + ncol];
    w1 = (unsigned)wp[(size_t)(8 + kw0 + 1) * 2048 + ncol];
    __syncthreads();

    f32x4 acc[4][4] = {};
    int pp = 0;

    #pragma unroll 2
    for (int t = 0; t < NT; ++t) {
        int nx = pp ^ 1;
        if (t + 1 < NT) {
            #pragma unroll
            for (int it = 0; it < 2; it++)
                gld16(aSrc[it] + (t + 1) * 64, &xs[nx][(wv * 2 + it) * 512]);
            unsigned o[4];
            dq_word(w0, s, o); *(int4*)&bs[nx][bd0] = make_int4(o[0], o[1], o[2], o[3]);
            dq_word(w1, s, o); *(int4*)&bs[nx][bd1] = make_int4(o[0], o[1], o[2], o[3]);
            if (t + 2 < NT) {
                s  = sc[(size_t)(t + 2) * 2048 + ncol];
                w0 = (unsigned)wp[(size_t)((t + 2) * 8 + kw0    ) * 2048 + ncol];
                w1 = (unsigned)wp[(size_t)((t + 2) * 8 + kw0 + 1) * 2048 + ncol];
            }
        }
        __builtin_amdgcn_s_setprio(1);
        #pragma unroll
        for (int ks = 0; ks < 2; ks++) {
            int slot = ((ks * 4 + quad) ^ l7) * 8;
            short8 a[4], b[4];
            #pragma unroll
            for (int mt = 0; mt < 4; mt++)
                a[mt] = *(const short8*)&xs[pp][(wr * 64 + mt * 16 + lid) * 64 + slot];
            #pragma unroll
            for (int nt = 0; nt < 4; nt++)
                b[nt] = *(const short8*)&bs[pp][(wc * 64 + nt * 16 + lid) * 64 + slot];
            #pragma unroll
            for (int mt = 0; mt < 4; mt++)
                #pragma unroll
                for (int nt = 0; nt < 4; nt++)
                    acc[mt][nt] = __builtin_amdgcn_mfma_f32_16x16x32_bf16(
                        a[mt], b[nt], acc[mt][nt], 0, 0, 0);
        }
        __builtin_amdgcn_s_setprio(0);
        __syncthreads();
        pp = nx;
    }

    int c7 = lid & 7;
    int delta = ((c7 >> 1) + ((c7 & 1) << 2)) - c7;   // sigma^-1 on stored I index
    #pragma unroll
    for (int mt = 0; mt < 4; mt++) {
        #pragma unroll
        for (int i = 0; i < 4; i++) {
            int row = wr * 64 + mt * 16 + quad * 4 + i;
            if (m0 + row < cnt) {
                size_t p = (size_t)(base + m0 + row);
                #pragma unroll
                for (int nt = 0; nt < 2; nt++) {
                    float g = acc[mt][nt][i], u = acc[mt][nt + 2][i];
                    float vv = g / (1.f + __expf(-g)) * u;
                    int ncol2 = n0 + wc * 32 + nt * 16 + lid;
                    __hip_bfloat16 hb = __float2bfloat16(vv);
                    act[p * I_DIM + ncol2 + delta] = *reinterpret_cast<ushort*>(&hb);
                }
            }
        }
    }
}

// ---- GEMM 2: y[p,n] = (act @ Wd)[p,n]. 256 rows x 256 cols, 1024 threads.
// Same single-barrier double-buffered fused-dequant pipeline as GEMM 1.
__global__ __launch_bounds__(1024) void k_gemm_down(
        const ushort* __restrict__ actb,
        const int* __restrict__ dwp, const float* __restrict__ dsc,
        const int* __restrict__ sdp, const float* __restrict__ sds,
        const int* __restrict__ gcnt, const int* __restrict__ gbase,
        const int* __restrict__ tileCnt, const int* __restrict__ tileE,
        const int* __restrict__ tileM,
        ushort* __restrict__ y) {
    int item = blockIdx.y;
    if (item >= *tileCnt) return;
    int tid = threadIdx.x;
    int e = tileE[item], m0 = tileM[item];
    int cnt = gcnt[e], base = gbase[e];
    int n0 = blockIdx.x * 256;
    const int* wp; const float* sc;
    if (e < NE) { wp = dwp + (size_t)e * 128 * 2048; sc = dsc + (size_t)e * 16 * 2048; }
    else        { wp = sdp; sc = sds; }

    __shared__ __align__(16) ushort xs[2][256 * 64];
    __shared__ __align__(16) ushort bs[2][256 * 64];

    int lane = tid & 63, wv = tid >> 6;
    int lid = lane & 15, quad = lane >> 4;
    int wr = wv >> 2, wc = wv & 3;
    int l8 = lane >> 3, l7 = lane & 7;
    int chunk = (l7 ^ l8) * 8;

    const ushort* aSrc[2];
    #pragma unroll
    for (int it = 0; it < 2; it++) {
        int rA = wv * 16 + it * 8 + l8;
        int rr = m0 + rA; if (rr >= cnt) rr = cnt - 1;
        aSrc[it] = actb + (size_t)(base + rr) * I_DIM + chunk;
    }

    int nloc = tid & 255;
    int kw0 = (tid >> 8) * 2;
    int ncol = n0 + nloc;
    int bd0 = nloc * 64 + ((kw0    ) ^ (nloc & 7)) * 8;
    int bd1 = nloc * 64 + ((kw0 + 1) ^ (nloc & 7)) * 8;

    const int NT = I_DIM / 64;                         // 16 i-tiles

    #pragma unroll
    for (int it = 0; it < 2; it++)
        gld16(aSrc[it], &xs[0][(wv * 2 + it) * 512]);
    float s   = sc[ncol];
    unsigned w0 = (unsigned)wp[(size_t)(kw0    ) * 2048 + ncol];
    unsigned w1 = (unsigned)wp[(size_t)(kw0 + 1) * 2048 + ncol];
    {
        unsigned o[4];
        dq_word(w0, s, o); *(int4*)&bs[0][bd0] = make_int4(o[0], o[1], o[2], o[3]);
        dq_word(w1, s, o); *(int4*)&bs[0][bd1] = make_int4(o[0], o[1], o[2], o[3]);
    }
    s  = sc[(size_t)2048 + ncol];
    w0 = (unsigned)wp[(size_t)(8 + kw0    ) * 2048 + ncol];
    w1 = (unsigned)wp[(size_t)(8 + kw0 + 1) * 2048 + ncol];
    __syncthreads();

    f32x4 acc[4][4] = {};
    int pp = 0;

    #pragma unroll 2
    for (int t = 0; t < NT; ++t) {
        int nx = pp ^ 1;
        if (t + 1 < NT) {
            #pragma unroll
            for (int it = 0; it < 2; it++)
                gld16(aSrc[it] + (t + 1) * 64, &xs[nx][(wv * 2 + it) * 512]);
            unsigned o[4];
            dq_word(w0, s, o); *(int4*)&bs[nx][bd0] = make_int4(o[0], o[1], o[2], o[3]);
            dq_word(w1, s, o); *(int4*)&bs[nx][bd1] = make_int4(o[0], o[1], o[2], o[3]);
            if (t + 2 < NT) {
                s  = sc[(size_t)(t + 2) * 2048 + ncol];
                w0 = (unsigned)wp[(size_t)((t + 2) * 8 + kw0    ) * 2048 + ncol];
                w1 = (unsigned)wp[(size_t)((t + 2) * 8 + kw0 + 1) * 2048 + ncol];
            }
        }
        __builtin_amdgcn_s_setprio(1);
        #pragma unroll
        for (int ks = 0; ks < 2; ks++) {
            int slot = ((ks * 4 + quad) ^ l7) * 8;
            short8 a[4], b[4];
            #pragma unroll
            for (int mt = 0; mt < 4; mt++)
                a[mt] = *(const short8*)&xs[pp][(wr * 64 + mt * 16 + lid) * 64 + slot];
            #pragma unroll
            for (int nt = 0; nt < 4; nt++)
                b[nt] = *(const short8*)&bs[pp][(wc * 64 + nt * 16 + lid) * 64 + slot];
            #pragma unroll
            for (int mt = 0; mt < 4; mt++)
                #pragma unroll
                for (int nt = 0; nt < 4; nt++)
                    acc[mt][nt] = __builtin_amdgcn_mfma_f32_16x16x32_bf16(
                        a[mt], b[nt], acc[mt][nt], 0, 0, 0);
        }
        __builtin_amdgcn_s_setprio(0);
        __syncthreads();
        pp = nx;
    }

    #pragma unroll
    for (int mt = 0; mt < 4; mt++) {
        #pragma unroll
        for (int i = 0; i < 4; i++) {
            int row = wr * 64 + mt * 16 + quad * 4 + i;
            if (m0 + row < cnt) {
                ushort* yrow = y + (size_t)(base + m0 + row) * 2048 + n0 + wc * 64 + lid;
                #pragma unroll
                for (int nt = 0; nt < 4; nt++) {
                    __hip_bfloat16 hb = __float2bfloat16(acc[mt][nt][i]);
                    yrow[nt * 16] = *reinterpret_cast<ushort*>(&hb);
                }
            }
        }
    }
}

// out[t] = p0*y[inv[2t]] + p1*y[inv[2t+1]] + y[NSLOT+t]
__global__ __launch_bounds__(256) void k_combine(
        const ushort* __restrict__ y, const int* __restrict__ inv,
        const float* __restrict__ prb, float* __restrict__ out) {
    int idx = blockIdx.x * 256 + threadIdx.x;
    int t = idx >> 8;
    int c = (idx & 255) * 8;
    int p0 = inv[2 * t], p1 = inv[2 * t + 1];
    float w0 = prb[2 * t], w1 = prb[2 * t + 1];
    int4 a = *(const int4*)(y + (size_t)p0 * 2048 + c);
    int4 b = *(const int4*)(y + (size_t)p1 * 2048 + c);
    int4 s = *(const int4*)(y + (size_t)(NSLOT + t) * 2048 + c);
    const ushort* au = (const ushort*)&a;
    const ushort* bu = (const ushort*)&b;
    const ushort* su = (const ushort*)&s;
    float o[8];
    #pragma unroll
    for (int j = 0; j < 8; j++)
        o[j] = w0 * bf2f(au[j]) + w1 * bf2f(bu[j]) + bf2f(su[j]);
    *(float4*)(out + (size_t)t * 2048 + c)     = *(float4*)&o[0];
    *(float4*)(out + (size_t)t * 2048 + c + 4) = *(float4*)&o[4];
}

extern "C" void kernel_launch(void* const* d_in, const int* in_sizes, int n_in,
                              void* d_out, int out_size, void* d_ws, size_t ws_size,
                              hipStream_t stream) {
    const float* x    = (const float*)d_in[0];
    const int*   gup  = (const int*)d_in[1];
    const float* gus  = (const float*)d_in[2];
    const int*   dwp  = (const int*)d_in[3];
    const float* dsc  = (const float*)d_in[4];
    const int*   sup  = (const int*)d_in[5];
    const float* sus  = (const float*)d_in[6];
    const int*   sdp  = (const int*)d_in[7];
    const float* sds  = (const float*)d_in[8];
    const int*   eids = (const int*)d_in[9];
    const float* prb  = (const float*)d_in[10];
    float* out = (float*)d_out;

    char*   ws      = (char*)d_ws;
    int*    gcnt    = (int*)(ws + 0);
    int*    gbase   = (int*)(ws + 64);
    int*    tileCnt = (int*)(ws + 128);
    int*    tileE   = (int*)(ws + 192);
    int*    tileM   = (int*)(ws + 448);
    int*    tok     = (int*)(ws + 1024);
    int*    inv     = (int*)(ws + 25600);
    ushort* xb      = (ushort*)(ws + WS_XB);
    ushort* act     = (ushort*)(ws + WS_ACT);
    ushort* y       = (ushort*)(ws + WS_Y);

    k_front<<<FRONT_GRID, 256, 0, stream>>>(
        x, xb, eids, gcnt, gbase, tileCnt, tileE, tileM, tok, inv);
    k_gemm_gateup<<<dim3(I_DIM / 128, MAXITEM), 1024, 0, stream>>>(
        xb, gup, gus, sup, sus, gcnt, gbase, tileCnt, tileE, tileM, tok, act);
    k_gemm_down<<<dim3(K_DIM / 256, MAXITEM), 1024, 0, stream>>>(
        act, dwp, dsc, sdp, sds, gcnt, gbase, tileCnt, tileE, tileM, y);
    k_combine<<<(T_TOK * K_DIM / 8) / 256, 256, 0, stream>>>(y, inv, prb, out);
}

// Round 3
// 228.461 us; speedup vs baseline: 1.0622x; 1.0173x over previous
//
#include <hip/hip_runtime.h>
#include <hip/hip_bf16.h>

// Problem constants (fixed instance)
#define T_TOK 2048
#define K_DIM 2048
#define I_DIM 1024
#define NE    8
#define TOPK  2
#define GS    64

#define NSLOT  (T_TOK * TOPK)      // 4096 routed slots
#define TOTROW (NSLOT + T_TOK)     // + shared-expert rows = 6144
#define MAXITEM 32                 // max (expert, 256-row m-tile) work items

typedef __attribute__((ext_vector_type(8))) short short8;   // 8 bf16 (MFMA A/B frag)
typedef __attribute__((ext_vector_type(4))) float f32x4;    // MFMA C/D frag

// ---- workspace layout (bytes) ----
// 0: gcnt[16] | 64: gbase[16] | 128: tileCnt | 192: tileE[64] | 448: tileM[64]
// 1024: tok[6144] | 25600: inv[4096]
#define WS_XB   ((size_t)65536)                        // ushort xb[2048][2048]
#define WS_ACT  (WS_XB  + (size_t)2048 * 2048 * 2)     // ushort act[TOTROW][1024]
#define WS_Y    (WS_ACT + (size_t)TOTROW * 1024 * 2)   // ushort y[TOTROW][2048]
// total ~46 MB (fp4->bf16 dequant fused into the GEMMs; no materialized weights)

// k-permutation sigma = {0,2,4,6,1,3,5,7} within each 8-block on BOTH operands
// (dot-product invariant); falls out of the byte-parallel nibble decode.

__device__ __forceinline__ unsigned pack2(float a, float b) {
    __hip_bfloat162 h = __float22bfloat162_rn(make_float2(a, b)); // x=low
    return *reinterpret_cast<unsigned*>(&h);
}

__device__ __forceinline__ unsigned scale2(unsigned p, float s) {
    float f0 = __uint_as_float(p << 16) * s;
    float f1 = __uint_as_float(p & 0xFFFF0000u) * s;
    return pack2(f0, f1);
}

__device__ __forceinline__ float bf2f(ushort h) {
    return __uint_as_float((unsigned)h << 16);
}

// one packed word (8 fp4 along k) -> 8 bf16 (sigma k-order) scaled by s
__device__ __forceinline__ void dq_word(unsigned w, float s, unsigned o[4]) {
    unsigned lo  = w & 0x0F0F0F0Fu;
    unsigned hi  = (w >> 4) & 0x0F0F0F0Fu;
    unsigned mlo = lo & 0x07070707u, mhi = hi & 0x07070707u;
    unsigned Hlo = __builtin_amdgcn_perm(0x40404040u, 0x3F3F3F00u, mlo);
    unsigned Hhi = __builtin_amdgcn_perm(0x40404040u, 0x3F3F3F00u, mhi);
    unsigned Llo = __builtin_amdgcn_perm(0xC0804000u, 0xC0800000u, mlo);
    unsigned Lhi = __builtin_amdgcn_perm(0xC0804000u, 0xC0800000u, mhi);
    Hlo |= (lo & 0x08080808u) << 4;
    Hhi |= (hi & 0x08080808u) << 4;
    unsigned e01 = __builtin_amdgcn_perm(Hlo, Llo, 0x05010400u);
    unsigned e23 = __builtin_amdgcn_perm(Hlo, Llo, 0x07030602u);
    unsigned o01 = __builtin_amdgcn_perm(Hhi, Lhi, 0x05010400u);
    unsigned o23 = __builtin_amdgcn_perm(Hhi, Lhi, 0x07030602u);
    o[0] = scale2(e01, s); o[1] = scale2(e23, s);
    o[2] = scale2(o01, s); o[3] = scale2(o23, s);
}

__device__ __forceinline__ void gld16(const void* g, void* l) {
    __builtin_amdgcn_global_load_lds(
        (const __attribute__((address_space(1))) unsigned*)g,
        (__attribute__((address_space(3))) unsigned*)l, 16, 0, 0);
}

// ---- front end: x prep + routing (weight dequant is fused into the GEMMs)
#define PREP_BLK 2048
#define FRONT_GRID (PREP_BLK + 1)

__global__ __launch_bounds__(256) void k_front(
        const float* __restrict__ x, ushort* __restrict__ xb,
        const int* __restrict__ eids,
        int* __restrict__ gcnt, int* __restrict__ gbase,
        int* __restrict__ tileCnt, int* __restrict__ tileE, int* __restrict__ tileM,
        int* __restrict__ tok, int* __restrict__ inv) {
    int id = blockIdx.x;
    int tid = threadIdx.x;

    if (id < PREP_BLK) {                              // x fp32 -> sigma-bf16
        int idx = id * 256 + tid;
        const float4* p = (const float4*)(x + (size_t)idx * 8);
        float4 f0 = p[0], f1 = p[1];
        unsigned u0 = pack2(f0.x, f0.z);
        unsigned u1 = pack2(f1.x, f1.z);
        unsigned u2 = pack2(f0.y, f0.w);
        unsigned u3 = pack2(f1.y, f1.w);
        *(int4*)(xb + (size_t)idx * 8) = make_int4(u0, u1, u2, u3);
    } else {                                           // routing + work-list
        __shared__ int lcnt[NE], lbase[NE], lcur[NE];
        if (tid < NE) lcnt[tid] = 0;
        __syncthreads();
        for (int i = tid; i < NSLOT; i += 256)
            atomicAdd(&lcnt[eids[i]], 1);
        __syncthreads();
        if (tid == 0) {
            int acc = 0;
            for (int e = 0; e < NE; e++) { lbase[e] = acc; acc += lcnt[e]; }
        }
        __syncthreads();
        if (tid < NE) lcur[tid] = lbase[tid];
        __syncthreads();
        for (int i = tid; i < NSLOT; i += 256) {
            int e = eids[i];
            int pos = atomicAdd(&lcur[e], 1);
            tok[pos] = i >> 1;
            inv[i] = pos;
        }
        for (int t = tid; t < T_TOK; t += 256)
            tok[NSLOT + t] = t;
        if (tid < NE) { gcnt[tid] = lcnt[tid]; gbase[tid] = lbase[tid]; }
        if (tid == 0) {
            gcnt[NE] = T_TOK; gbase[NE] = NSLOT;
            int nt = 0;
            for (int e = 0; e < NE + 1; e++) {
                int c = (e < NE) ? lcnt[e] : T_TOK;
                for (int m = 0; m < c; m += 256) { tileE[nt] = e; tileM[nt] = m; nt++; }
            }
            *tileCnt = nt;                             // <= 32
            for (int i = nt; i < 64; i++) { tileE[i] = 0; tileM[i] = 0; }
        }
    }
}

// ---- GEMM 1: act[p,n] = silu(x@Wg)*(x@Wu). 256 rows x (64 gate + 64 up) per
// block, 512 threads = 8 waves (4x2 of 64x64 wave-tiles), BK=64, XOR-swizzle.
// LDS 48 KB single-buffer -> 2 blocks/CU co-resident: one block's MFMA phase
// covers the other's stage/barrier stalls (this was the r0 mechanism; r2's
// 128 KB dbuf lost it). B (gate_up weights) dequanted fp4->bf16 in staging;
// packed words register-prefetched one k-step ahead via pointer bumps.
__global__ __launch_bounds__(512) void k_gemm_gateup(
        const ushort* __restrict__ xb,
        const int* __restrict__ gup, const float* __restrict__ gus,
        const int* __restrict__ sup, const float* __restrict__ sus,
        const int* __restrict__ gcnt, const int* __restrict__ gbase,
        const int* __restrict__ tileCnt, const int* __restrict__ tileE,
        const int* __restrict__ tileM,
        const int* __restrict__ tokid, ushort* __restrict__ act) {
    int item = blockIdx.y;
    if (item >= *tileCnt) return;
    int tid = threadIdx.x;
    int e = tileE[item], m0 = tileM[item];
    int cnt = gcnt[e], base = gbase[e];
    int n0 = blockIdx.x * 64;                          // gate-col base (64 wide)
    const int* wp; const float* sc;
    if (e < NE) { wp = gup + (size_t)e * 256 * 2048; sc = gus + (size_t)e * 32 * 2048; }
    else        { wp = sup; sc = sus; }

    __shared__ __align__(16) ushort xs[256 * 64];      // 32 KB
    __shared__ __align__(16) ushort bs[128 * 64];      // 16 KB (48 KB total)

    int lane = tid & 63, wv = tid >> 6;                // 8 waves
    int lid = lane & 15, quad = lane >> 4;
    int wr = wv >> 1, wc = wv & 1;                     // 4x2 waves of 64x64
    int l8 = lane >> 3, l7 = lane & 7;
    int chunk = (l7 ^ l8) * 8;

    // A staging: 4 rows-groups per lane (32 rows/wave), pre-swizzled source
    const ushort* aSrc[4];
    #pragma unroll
    for (int it = 0; it < 4; it++) {
        int rA = wv * 32 + it * 8 + l8;                // rA & 7 == l8
        int t = (m0 + rA < cnt) ? tokid[base + m0 + rA] : 0;
        aSrc[it] = xb + (size_t)t * K_DIM + chunk;
    }

    // B fused dequant: thread owns col nloc (of 128), k-words {kw0, kw0+1}
    int nloc = tid & 127;
    int kw0 = (tid >> 7) * 2;                          // {0,2,4,6}
    int bj = nloc & 63, bh = nloc >> 6;
    int ncol = (bj < 32) ? (n0 + bh * 32 + bj) : (I_DIM + n0 + bh * 32 + (bj - 32));
    int bd0 = nloc * 64 + ((kw0    ) ^ (nloc & 7)) * 8;
    int bd1 = nloc * 64 + ((kw0 + 1) ^ (nloc & 7)) * 8;

    const int NT = K_DIM / 64;                         // 32 k-tiles
    const int* wq = wp + (size_t)kw0 * 2048 + ncol;
    const float* sq = sc + ncol;
    unsigned w0 = (unsigned)wq[0];
    unsigned w1 = (unsigned)wq[2048];
    float s = *sq;
    wq += 16384; sq += 2048;

    f32x4 acc[4][4] = {};

    for (int t = 0; t < NT; ++t) {
        #pragma unroll
        for (int it = 0; it < 4; it++) {
            gld16(aSrc[it], &xs[(wv * 4 + it) * 512]);
            aSrc[it] += 64;
        }
        {
            unsigned o[4];
            dq_word(w0, s, o); *(int4*)&bs[bd0] = make_int4(o[0], o[1], o[2], o[3]);
            dq_word(w1, s, o); *(int4*)&bs[bd1] = make_int4(o[0], o[1], o[2], o[3]);
        }
        if (t + 1 < NT) {                              // prefetch next k-step B
            w0 = (unsigned)wq[0];
            w1 = (unsigned)wq[2048];
            s = *sq;
            wq += 16384; sq += 2048;
        }
        __syncthreads();
        __builtin_amdgcn_s_setprio(1);
        #pragma unroll
        for (int ks = 0; ks < 2; ks++) {
            int slot = ((ks * 4 + quad) ^ l7) * 8;
            short8 a[4], b[4];
            #pragma unroll
            for (int mt = 0; mt < 4; mt++)
                a[mt] = *(const short8*)&xs[(wr * 64 + mt * 16 + lid) * 64 + slot];
            #pragma unroll
            for (int nt = 0; nt < 4; nt++)
                b[nt] = *(const short8*)&bs[(wc * 64 + nt * 16 + lid) * 64 + slot];
            #pragma unroll
            for (int mt = 0; mt < 4; mt++)
                #pragma unroll
                for (int nt = 0; nt < 4; nt++)
                    acc[mt][nt] = __builtin_amdgcn_mfma_f32_16x16x32_bf16(
                        a[mt], b[nt], acc[mt][nt], 0, 0, 0);
        }
        __builtin_amdgcn_s_setprio(0);
        __syncthreads();
    }

    int c7 = lid & 7;
    int delta = ((c7 >> 1) + ((c7 & 1) << 2)) - c7;   // sigma^-1 on stored I index
    #pragma unroll
    for (int mt = 0; mt < 4; mt++) {
        #pragma unroll
        for (int i = 0; i < 4; i++) {
            int row = wr * 64 + mt * 16 + quad * 4 + i;
            if (m0 + row < cnt) {
                size_t p = (size_t)(base + m0 + row);
                #pragma unroll
                for (int nt = 0; nt < 2; nt++) {
                    float g = acc[mt][nt][i], u = acc[mt][nt + 2][i];
                    float vv = g / (1.f + __expf(-g)) * u;
                    int ncol2 = n0 + wc * 32 + nt * 16 + lid;
                    __hip_bfloat16 hb = __float2bfloat16(vv);
                    act[p * I_DIM + ncol2 + delta] = *reinterpret_cast<ushort*>(&hb);
                }
            }
        }
    }
}

// ---- GEMM 2: y[p,n] = (act @ Wd)[p,n]. 256 rows x 128 cols, 512 threads,
// same 8-wave / 48 KB / 2-blocks-per-CU structure as GEMM 1.
__global__ __launch_bounds__(512) void k_gemm_down(
        const ushort* __restrict__ actb,
        const int* __restrict__ dwp, const float* __restrict__ dsc,
        const int* __restrict__ sdp, const float* __restrict__ sds,
        const int* __restrict__ gcnt, const int* __restrict__ gbase,
        const int* __restrict__ tileCnt, const int* __restrict__ tileE,
        const int* __restrict__ tileM,
        ushort* __restrict__ y) {
    int item = blockIdx.y;
    if (item >= *tileCnt) return;
    int tid = threadIdx.x;
    int e = tileE[item], m0 = tileM[item];
    int cnt = gcnt[e], base = gbase[e];
    int n0 = blockIdx.x * 128;
    const int* wp; const float* sc;
    if (e < NE) { wp = dwp + (size_t)e * 128 * 2048; sc = dsc + (size_t)e * 16 * 2048; }
    else        { wp = sdp; sc = sds; }

    __shared__ __align__(16) ushort xs[256 * 64];      // 32 KB
    __shared__ __align__(16) ushort bs[128 * 64];      // 16 KB

    int lane = tid & 63, wv = tid >> 6;
    int lid = lane & 15, quad = lane >> 4;
    int wr = wv >> 1, wc = wv & 1;
    int l8 = lane >> 3, l7 = lane & 7;
    int chunk = (l7 ^ l8) * 8;

    const ushort* aSrc[4];
    #pragma unroll
    for (int it = 0; it < 4; it++) {
        int rA = wv * 32 + it * 8 + l8;
        int rr = m0 + rA; if (rr >= cnt) rr = cnt - 1;
        aSrc[it] = actb + (size_t)(base + rr) * I_DIM + chunk;
    }

    int nloc = tid & 127;
    int kw0 = (tid >> 7) * 2;
    int ncol = n0 + nloc;
    int bd0 = nloc * 64 + ((kw0    ) ^ (nloc & 7)) * 8;
    int bd1 = nloc * 64 + ((kw0 + 1) ^ (nloc & 7)) * 8;

    const int NT = I_DIM / 64;                         // 16 i-tiles
    const int* wq = wp + (size_t)kw0 * 2048 + ncol;
    const float* sq = sc + ncol;
    unsigned w0 = (unsigned)wq[0];
    unsigned w1 = (unsigned)wq[2048];
    float s = *sq;
    wq += 16384; sq += 2048;

    f32x4 acc[4][4] = {};

    for (int t = 0; t < NT; ++t) {
        #pragma unroll
        for (int it = 0; it < 4; it++) {
            gld16(aSrc[it], &xs[(wv * 4 + it) * 512]);
            aSrc[it] += 64;
        }
        {
            unsigned o[4];
            dq_word(w0, s, o); *(int4*)&bs[bd0] = make_int4(o[0], o[1], o[2], o[3]);
            dq_word(w1, s, o); *(int4*)&bs[bd1] = make_int4(o[0], o[1], o[2], o[3]);
        }
        if (t + 1 < NT) {
            w0 = (unsigned)wq[0];
            w1 = (unsigned)wq[2048];
            s = *sq;
            wq += 16384; sq += 2048;
        }
        __syncthreads();
        __builtin_amdgcn_s_setprio(1);
        #pragma unroll
        for (int ks = 0; ks < 2; ks++) {
            int slot = ((ks * 4 + quad) ^ l7) * 8;
            short8 a[4], b[4];
            #pragma unroll
            for (int mt = 0; mt < 4; mt++)
                a[mt] = *(const short8*)&xs[(wr * 64 + mt * 16 + lid) * 64 + slot];
            #pragma unroll
            for (int nt = 0; nt < 4; nt++)
                b[nt] = *(const short8*)&bs[(wc * 64 + nt * 16 + lid) * 64 + slot];
            #pragma unroll
            for (int mt = 0; mt < 4; mt++)
                #pragma unroll
                for (int nt = 0; nt < 4; nt++)
                    acc[mt][nt] = __builtin_amdgcn_mfma_f32_16x16x32_bf16(
                        a[mt], b[nt], acc[mt][nt], 0, 0, 0);
        }
        __builtin_amdgcn_s_setprio(0);
        __syncthreads();
    }

    #pragma unroll
    for (int mt = 0; mt < 4; mt++) {
        #pragma unroll
        for (int i = 0; i < 4; i++) {
            int row = wr * 64 + mt * 16 + quad * 4 + i;
            if (m0 + row < cnt) {
                ushort* yrow = y + (size_t)(base + m0 + row) * 2048 + n0 + wc * 64 + lid;
                #pragma unroll
                for (int nt = 0; nt < 4; nt++) {
                    __hip_bfloat16 hb = __float2bfloat16(acc[mt][nt][i]);
                    yrow[nt * 16] = *reinterpret_cast<ushort*>(&hb);
                }
            }
        }
    }
}

// out[t] = p0*y[inv[2t]] + p1*y[inv[2t+1]] + y[NSLOT+t]
__global__ __launch_bounds__(256) void k_combine(
        const ushort* __restrict__ y, const int* __restrict__ inv,
        const float* __restrict__ prb, float* __restrict__ out) {
    int idx = blockIdx.x * 256 + threadIdx.x;
    int t = idx >> 8;
    int c = (idx & 255) * 8;
    int p0 = inv[2 * t], p1 = inv[2 * t + 1];
    float w0 = prb[2 * t], w1 = prb[2 * t + 1];
    int4 a = *(const int4*)(y + (size_t)p0 * 2048 + c);
    int4 b = *(const int4*)(y + (size_t)p1 * 2048 + c);
    int4 s = *(const int4*)(y + (size_t)(NSLOT + t) * 2048 + c);
    const ushort* au = (const ushort*)&a;
    const ushort* bu = (const ushort*)&b;
    const ushort* su = (const ushort*)&s;
    float o[8];
    #pragma unroll
    for (int j = 0; j < 8; j++)
        o[j] = w0 * bf2f(au[j]) + w1 * bf2f(bu[j]) + bf2f(su[j]);
    *(float4*)(out + (size_t)t * 2048 + c)     = *(float4*)&o[0];
    *(float4*)(out + (size_t)t * 2048 + c + 4) = *(float4*)&o[4];
}

extern "C" void kernel_launch(void* const* d_in, const int* in_sizes, int n_in,
                              void* d_out, int out_size, void* d_ws, size_t ws_size,
                              hipStream_t stream) {
    const float* x    = (const float*)d_in[0];
    const int*   gup  = (const int*)d_in[1];
    const float* gus  = (const float*)d_in[2];
    const int*   dwp  = (const int*)d_in[3];
    const float* dsc  = (const float*)d_in[4];
    const int*   sup  = (const int*)d_in[5];
    const float* sus  = (const float*)d_in[6];
    const int*   sdp  = (const int*)d_in[7];
    const float* sds  = (const float*)d_in[8];
    const int*   eids = (const int*)d_in[9];
    const float* prb  = (const float*)d_in[10];
    float* out = (float*)d_out;

    char*   ws      = (char*)d_ws;
    int*    gcnt    = (int*)(ws + 0);
    int*    gbase   = (int*)(ws + 64);
    int*    tileCnt = (int*)(ws + 128);
    int*    tileE   = (int*)(ws + 192);
    int*    tileM   = (int*)(ws + 448);
    int*    tok     = (int*)(ws + 1024);
    int*    inv     = (int*)(ws + 25600);
    ushort* xb      = (ushort*)(ws + WS_XB);
    ushort* act     = (ushort*)(ws + WS_ACT);
    ushort* y       = (ushort*)(ws + WS_Y);

    k_front<<<FRONT_GRID, 256, 0, stream>>>(
        x, xb, eids, gcnt, gbase, tileCnt, tileE, tileM, tok, inv);
    k_gemm_gateup<<<dim3(I_DIM / 64, MAXITEM), 512, 0, stream>>>(
        xb, gup, gus, sup, sus, gcnt, gbase, tileCnt, tileE, tileM, tok, act);
    k_gemm_down<<<dim3(K_DIM / 128, MAXITEM), 512, 0, stream>>>(
        act, dwp, dsc, sdp, sds, gcnt, gbase, tileCnt, tileE, tileM, y);
    k_combine<<<(T_TOK * K_DIM / 8) / 256, 256, 0, stream>>>(y, inv, prb, out);
}